// Round 10
// baseline (168.648 us; speedup 1.0000x reference)
//
#include <hip/hip_runtime.h>

// Problem constants
#define B_ 8
#define N_ 1024
#define F_ 256
#define O_ 256

typedef unsigned short u16;
typedef unsigned int u32;
typedef __attribute__((ext_vector_type(8))) short bf8;   // 8 bf16 (4 VGPRs) MFMA frag
typedef __attribute__((ext_vector_type(4))) float f4;    // 4 fp32 MFMA acc

__device__ __forceinline__ u16 f2bf(float f) {
  union { float f; u32 u; } c; c.f = f;
  u32 u = c.u;
  u32 r = u + 0x7FFFu + ((u >> 16) & 1u);  // RNE
  return (u16)(r >> 16);
}
__device__ __forceinline__ float bf2f(u16 u) {
  union { u32 i; float f; } c; c.i = ((u32)u) << 16; return c.f;
}

#if defined(__has_builtin)
#if __has_builtin(__builtin_amdgcn_perm)
#define HAVE_PERM 1
#endif
#endif
__device__ __forceinline__ u32 dup01(u32 e) {  // bytes (b0,b0,b1,b1)
#ifdef HAVE_PERM
  return __builtin_amdgcn_perm(e, e, 0x01010000u);
#else
  return (e & 0xFFu) * 0x0101u + (e & 0xFF00u) * 0x010100u;
#endif
}
__device__ __forceinline__ u32 dup23(u32 e) {  // bytes (b2,b2,b3,b3)
#ifdef HAVE_PERM
  return __builtin_amdgcn_perm(e, e, 0x03030202u);
#else
  return ((e >> 16) & 0xFFu) * 0x0101u + ((e >> 16) & 0xFF00u) * 0x010100u;
#endif
}

// ---------------------------------------------------------------------------
// K_prep: fused {W transpose+head-sum} | {vsrc/vdst dots} | {nibble masks}.
__global__ __launch_bounds__(256) void k_prep(const float* __restrict__ W,
                                              const float* __restrict__ a,
                                              u16* __restrict__ Wt,
                                              float* __restrict__ vsrc,
                                              float* __restrict__ vdst,
                                              const int* __restrict__ AU,
                                              const int* __restrict__ AD,
                                              const int* __restrict__ AR,
                                              const int* __restrict__ AL,
                                              unsigned char* __restrict__ nibR,
                                              unsigned char* __restrict__ nibF) {
  __shared__ u16 t[64][72];
  __shared__ float red[2][4];
  int bx = blockIdx.x;
  int tdx = threadIdx.x;
  if (bx < 64) {
    int d = bx >> 4, tile = bx & 15;
    int f0 = (tile >> 2) * 64, o0 = (tile & 3) * 64;
    const float* src0 = W + (d * 2 + 0) * 65536;
    const float* src1 = W + (d * 2 + 1) * 65536;
    u16* dst = Wt + d * 65536;
    for (int i = 0; i < 2; ++i) {
      int c = i * 256 + tdx;
      int row = c >> 3, cc = (c & 7) * 8;
      int base = (f0 + row) * 256 + o0 + cc;
      float4 a0 = *(const float4*)&src0[base];
      float4 a1 = *(const float4*)&src0[base + 4];
      float4 b0 = *(const float4*)&src1[base];
      float4 b1 = *(const float4*)&src1[base + 4];
      u16 tmp[8] __attribute__((aligned(16)));
      tmp[0] = f2bf(a0.x + b0.x); tmp[1] = f2bf(a0.y + b0.y);
      tmp[2] = f2bf(a0.z + b0.z); tmp[3] = f2bf(a0.w + b0.w);
      tmp[4] = f2bf(a1.x + b1.x); tmp[5] = f2bf(a1.y + b1.y);
      tmp[6] = f2bf(a1.z + b1.z); tmp[7] = f2bf(a1.w + b1.w);
      *(uint4*)&t[row][cc] = *(uint4*)tmp;
    }
    __syncthreads();
    for (int i = 0; i < 2; ++i) {
      int c = i * 256 + tdx;
      int orow = c >> 3, fc = (c & 7) * 8;
      u16 v[8] __attribute__((aligned(16)));
#pragma unroll
      for (int k = 0; k < 8; ++k) v[k] = t[fc + k][orow];
      *(uint4*)&dst[(o0 + orow) * 256 + f0 + fc] = *(uint4*)v;
    }
  } else if (bx < 1088) {
    int blk = bx - 64;
    int d = blk >> 8, f = blk & 255;
    int o = tdx;
    int dh = d * 2 + 1;
    float w = W[(dh * 256 + f) * 256 + o];
    float as = a[dh * 512 + o];
    float ad = a[dh * 512 + 256 + o];
    float ps = w * as, pd = w * ad;
    for (int off = 32; off; off >>= 1) {
      ps += __shfl_down(ps, off);
      pd += __shfl_down(pd, off);
    }
    int lane = o & 63, w4 = o >> 6;
    if (lane == 0) { red[0][w4] = ps; red[1][w4] = pd; }
    __syncthreads();
    if (o == 0) vsrc[d * 256 + f] = red[0][0] + red[0][1] + red[0][2] + red[0][3];
    if (o == 1) vdst[d * 256 + f] = red[1][0] + red[1][1] + red[1][2] + red[1][3];
  } else {
    int idx = (bx - 1088) * 256 + tdx;  // 131072: i*128 + j/8
    int i = idx >> 7;
    int jb = (idx & 127) * 8;
    int base = i * 1024 + jb;
    int4 au0 = *(const int4*)&AU[base], au1 = *(const int4*)&AU[base + 4];
    int4 ad0 = *(const int4*)&AD[base], ad1 = *(const int4*)&AD[base + 4];
    int4 ar0 = *(const int4*)&AR[base], ar1 = *(const int4*)&AR[base + 4];
    int4 al0 = *(const int4*)&AL[base], al1 = *(const int4*)&AL[base + 4];
    int u[8] = {au0.x, au0.y, au0.z, au0.w, au1.x, au1.y, au1.z, au1.w};
    int dn[8] = {ad0.x, ad0.y, ad0.z, ad0.w, ad1.x, ad1.y, ad1.z, ad1.w};
    int rr[8] = {ar0.x, ar0.y, ar0.z, ar0.w, ar1.x, ar1.y, ar1.z, ar1.w};
    int ll[8] = {al0.x, al0.y, al0.z, al0.w, al1.x, al1.y, al1.z, al1.w};
    unsigned char m[8] __attribute__((aligned(8)));
#pragma unroll
    for (int k = 0; k < 8; ++k)
      m[k] = (unsigned char)((u[k] ? 1u : 0u) | (dn[k] ? 2u : 0u) | (rr[k] ? 4u : 0u) | (ll[k] ? 8u : 0u));
    *(uint2*)&nibR[base] = *(uint2*)m;
    int it = i >> 4, jw = jb >> 5;
    int lane = ((jb >> 3) & 3) * 16 + (i & 15);
    *(uint2*)&nibF[((it * 32 + jw) * 64 + lane) * 8] = *(uint2*)m;
  }
}

// ---------------------------------------------------------------------------
// K2: wave-per-4-rows e-dots + xb emit.
__global__ __launch_bounds__(256) void k_edots(const float* __restrict__ x,
                                               const float* __restrict__ vsrc,
                                               const float* __restrict__ vdst,
                                               float* __restrict__ es,
                                               float* __restrict__ ed,
                                               u16* __restrict__ xb) {
  int t = threadIdx.x, lane = t & 63, w = t >> 6;
  int f4i = lane * 4;
  float4 vs[4], vd[4];
#pragma unroll
  for (int d = 0; d < 4; ++d) {
    vs[d] = *(const float4*)&vsrc[d * 256 + f4i];
    vd[d] = *(const float4*)&vdst[d * 256 + f4i];
  }
  int row0 = blockIdx.x * 16 + w * 4;  // 512 blocks x 16 rows
  for (int rr = 0; rr < 4; ++rr) {
    int row = row0 + rr;
    float4 xv = *(const float4*)&x[(size_t)row * 256 + f4i];
    u16 pk[4] __attribute__((aligned(8)));
    pk[0] = f2bf(xv.x); pk[1] = f2bf(xv.y); pk[2] = f2bf(xv.z); pk[3] = f2bf(xv.w);
    *(uint2*)&xb[(size_t)row * 256 + f4i] = *(uint2*)pk;
    float p[8];
#pragma unroll
    for (int d = 0; d < 4; ++d) {
      p[d] = xv.x * vs[d].x + xv.y * vs[d].y + xv.z * vs[d].z + xv.w * vs[d].w;
      p[4 + d] = xv.x * vd[d].x + xv.y * vd[d].y + xv.z * vd[d].z + xv.w * vd[d].w;
    }
#pragma unroll
    for (int v = 0; v < 8; ++v)
      for (int off = 32; off; off >>= 1) p[v] += __shfl_xor(p[v], off);
    if (lane == 0) {
      int b = row >> 10, n = row & 1023;
#pragma unroll
      for (int d = 0; d < 4; ++d) {
        es[(d * 8 + b) * 1024 + n] = p[d];
        ed[(d * 8 + b) * 1024 + n] = p[4 + d];
      }
    }
  }
}

// ---------------------------------------------------------------------------
// K_mid: fused {whsum MFMA GEMM (BK=64, 8 barriers)} | {softmax}.
__global__ __launch_bounds__(256, 2) void k_mid(const u16* __restrict__ X,
                                                const u16* __restrict__ Wt,
                                                u16* __restrict__ WhstF,
                                                const float* __restrict__ es,
                                                const float* __restrict__ ed,
                                                const unsigned char* __restrict__ nibR,
                                                u16* __restrict__ alphaF) {
  __shared__ char smem[51200];
  int bx = blockIdx.x;
  int t = threadIdx.x;
  int lane = t & 63, w = t >> 6;
  if (bx < 512) {
    // ---- whsum, BK=64 with 72-halfword padded stride (4-bank row rotation)
    u16* lA = (u16*)smem;                   // 128*72*2 = 18432 B
    u16* lB = (u16*)(smem + 18432);         // 18432 B
    u16* sC = (u16*)smem;                   // reused after K-loop (34816 B)
    int xo = bx & 1;
    int m0 = ((bx >> 1) & 63) * 128;
    int d = bx >> 7;
    int o0 = xo * 128;
    int wm = w >> 1, wn = w & 1;
    int r16 = lane & 15, quad = lane >> 4, q8 = quad * 8;
    f4 acc[4][4];
    const f4 fz = {0.f, 0.f, 0.f, 0.f};
#pragma unroll
    for (int i = 0; i < 4; ++i)
#pragma unroll
      for (int j = 0; j < 4; ++j) acc[i][j] = fz;

    const u16* Bp = Wt + d * 65536;
    for (int k0 = 0; k0 < 256; k0 += 64) {
      uint4 va[4], vb[4];
#pragma unroll
      for (int i = 0; i < 4; ++i) {
        int c = i * 256 + t;                 // 1024 chunks (16B) per tile
        int row = c >> 3, ko = (c & 7) * 8;  // 8 chunks per 64-wide row
        va[i] = *(const uint4*)&X[(size_t)(m0 + row) * 256 + k0 + ko];
        vb[i] = *(const uint4*)&Bp[(o0 + row) * 256 + k0 + ko];
      }
      __syncthreads();
#pragma unroll
      for (int i = 0; i < 4; ++i) {
        int c = i * 256 + t;
        int row = c >> 3, ko = (c & 7) * 8;
        *(uint4*)&lA[row * 72 + ko] = va[i];
        *(uint4*)&lB[row * 72 + ko] = vb[i];
      }
      __syncthreads();
#pragma unroll
      for (int sub = 0; sub < 2; ++sub) {
        bf8 af[4], bfr[4];
#pragma unroll
        for (int tm = 0; tm < 4; ++tm)
          af[tm] = *(const bf8*)&lA[(wm * 64 + tm * 16 + r16) * 72 + sub * 32 + q8];
#pragma unroll
        for (int tn = 0; tn < 4; ++tn)
          bfr[tn] = *(const bf8*)&lB[(wn * 64 + tn * 16 + r16) * 72 + sub * 32 + q8];
#pragma unroll
        for (int tm = 0; tm < 4; ++tm)
#pragma unroll
          for (int tn = 0; tn < 4; ++tn)
            acc[tm][tn] = __builtin_amdgcn_mfma_f32_16x16x32_bf16(
                af[tm], bfr[tn], acc[tm][tn], 0, 0, 0);
      }
    }
    __syncthreads();  // all waves done reading lA/lB; safe to overwrite with sC
#pragma unroll
    for (int tm = 0; tm < 4; ++tm) {
#pragma unroll
      for (int tn = 0; tn < 4; ++tn) {
        int o = wn * 64 + tn * 16 + r16;
        int n = wm * 64 + tm * 16 + quad * 4;
        u16 p[4] __attribute__((aligned(8)));
#pragma unroll
        for (int r = 0; r < 4; ++r) p[r] = f2bf(acc[tm][tn][r]);
        *(uint2*)&sC[o * 136 + n] = *(uint2*)p;
      }
    }
    __syncthreads();
    int b = m0 >> 10;
    int nlo = m0 & 1023;
    int dbbase = d * 8 + b;
    int otg0 = o0 >> 4, jwg0 = nlo >> 5;
#pragma unroll
    for (int cc = 0; cc < 8; ++cc) {
      int c = cc * 256 + t;
      int p = c >> 6, l = c & 63;
      int ot_l = p >> 2, jw_l = p & 3;
      int o_l = ot_l * 16 + (l & 15);
      int j_l = jw_l * 32 + (l >> 4) * 8;
      uint4 v = *(const uint4*)&sC[o_l * 136 + j_l];
      int off = (((dbbase * 16 + otg0 + ot_l) * 32 + jwg0 + jw_l) * 64 + l) * 8;
      *(uint4*)&WhstF[off] = v;
    }
  } else {
    // ---- softmax -> alphaF (frag-ordered). ed cached in LDS; single pass.
    float* sEd = (float*)smem;                       // 16384 B
    u16 (*sAl)[1032] = (u16(*)[1032])(smem + 16384); // 33024 B
    float* srs = (float*)(smem + 49408);             //    64 B
    int sx = bx - 512;
    int it = sx & 63, b = sx >> 6;
    const float NINF = -__builtin_inff();
#pragma unroll
    for (int c = 0; c < 4; ++c) {
      int q = c * 256 + t;
      int d = q >> 8, jc = (q & 255) * 4;
      *(float4*)&sEd[d * 1024 + jc] = *(const float4*)&ed[(size_t)(d * 8 + b) * 1024 + jc];
    }
    __syncthreads();
    for (int rr = 0; rr < 4; ++rr) {
      int r = w * 4 + rr;
      int i = it * 16 + r;
      float e0 = es[(0 * 8 + b) * 1024 + i];
      float e1 = es[(1 * 8 + b) * 1024 + i];
      float e2 = es[(2 * 8 + b) * 1024 + i];
      float e3 = es[(3 * 8 + b) * 1024 + i];
      unsigned mbv[16];
#pragma unroll
      for (int k = 0; k < 16; ++k) mbv[k] = nibR[i * 1024 + k * 64 + lane];
      float e[16];
      float mx = NINF;
#pragma unroll
      for (int k = 0; k < 16; ++k) {
        unsigned m = mbv[k];
        int d = m ? (31 - __clz((int)m)) : 0;
        float esd = d == 0 ? e0 : d == 1 ? e1 : d == 2 ? e2 : e3;
        float z = esd + sEd[d * 1024 + k * 64 + lane];
        float lz = z > 0.0f ? z : 0.01f * z;
        e[k] = m ? lz : NINF;
        mx = fmaxf(mx, e[k]);
      }
      for (int off = 32; off; off >>= 1) mx = fmaxf(mx, __shfl_xor(mx, off));
      float s = 0.f;
#pragma unroll
      for (int k = 0; k < 16; ++k) {
        float p = exp2f((e[k] - mx) * 1.4426950408889634f);
        s += p;
        sAl[r][k * 64 + lane] = f2bf(p);
      }
      for (int off = 32; off; off >>= 1) s += __shfl_xor(s, off);
      if (lane == 0) srs[r] = 1.0f / s;
    }
    __syncthreads();
#pragma unroll
    for (int cc = 0; cc < 8; ++cc) {
      int c = cc * 256 + t;
      int jw = c >> 6, l = c & 63;
      int i_l = l & 15;
      int j_l = jw * 32 + (l >> 4) * 8;
      uint4 v = *(const uint4*)&sAl[i_l][j_l];
      float rs = srs[i_l];
      u16 pk[8] __attribute__((aligned(16)));
      u32 wv[4] = {v.x, v.y, v.z, v.w};
#pragma unroll
      for (int k = 0; k < 4; ++k) {
        pk[k * 2] = f2bf(bf2f((u16)(wv[k] & 0xFFFFu)) * rs);
        pk[k * 2 + 1] = f2bf(bf2f((u16)(wv[k] >> 16)) * rs);
      }
      int off = (((b * 64 + it) * 32 + jw) * 64 + l) * 8;
      *(uint4*)&alphaF[off] = *(uint4*)pk;
    }
  }
}

// ---------------------------------------------------------------------------
// K6 (R10): 1024 blocks (128i x 64o each; waves 64i x 32o) for 3 blocks/CU
// TLP. B 3-slot rotation, 2-step lookahead; A/nib double-buffered per js.
__global__ __launch_bounds__(256, 3) void k_agg(const u16* __restrict__ alphaF,
                                                const unsigned char* __restrict__ nibF,
                                                const u16* __restrict__ WhstF,
                                                u16* __restrict__ part) {
  int ob4 = blockIdx.x;        // 4: o-quarter (4 o-tiles each)
  int bz = blockIdx.y;         // 32: b*4 + ks
  int iz = blockIdx.z;         // 8: i-tile-128
  int b = bz >> 2, ks = bz & 3;
  int t = threadIdx.x, lane = t & 63, w = t >> 6;
  int wm = w >> 1, wn = w & 1;
  int r16 = lane & 15, quad = lane >> 4;
  int itb = iz * 8 + wm * 4;   // 4 i-tiles per wave
  int otb = ob4 * 4 + wn * 2;  // 2 o-tiles per wave
  int jw0 = ks * 8;

  int aoff[4], noff[4], bo[4];
#pragma unroll
  for (int tm = 0; tm < 4; ++tm) {
    aoff[tm] = (((b * 64 + itb + tm) * 32 + jw0) * 64 + lane) * 8;
    noff[tm] = (((itb + tm) * 32 + jw0) * 64 + lane) * 8;
  }
#pragma unroll
  for (int d = 0; d < 4; ++d)
    bo[d] = ((((d * 8 + b) * 16 + otb) * 32 + jw0) * 64 + lane) * 8;

  f4 acc[4][2];
  const f4 fz = {0.f, 0.f, 0.f, 0.f};
#pragma unroll
  for (int i = 0; i < 4; ++i) { acc[i][0] = fz; acc[i][1] = fz; }

  uint4 A[2][4];
  uint2 Nn[2][4];
  uint4 Bb[3][2];
  union U { uint4 u; bf8 h; };

#pragma unroll
  for (int tm = 0; tm < 4; ++tm) {
    A[0][tm] = *(const uint4*)&alphaF[aoff[tm]];
    Nn[0][tm] = *(const uint2*)&nibF[noff[tm]];
  }
#pragma unroll
  for (int s = 0; s < 2; ++s)
#pragma unroll
    for (int tn = 0; tn < 2; ++tn)
      Bb[s][tn] = *(const uint4*)&WhstF[bo[s] + tn * 16384];

#pragma unroll
  for (int js = 0; js < 8; ++js) {
    int cs = js & 1;
    if (js < 7) {
#pragma unroll
      for (int tm = 0; tm < 4; ++tm) {
        A[cs ^ 1][tm] = *(const uint4*)&alphaF[aoff[tm] + (js + 1) * 512];
        Nn[cs ^ 1][tm] = *(const uint2*)&nibF[noff[tm] + (js + 1) * 512];
      }
    }
#pragma unroll
    for (int d = 0; d < 4; ++d) {
      int s = js * 4 + d;
      if (s + 2 < 32) {
        int js2 = (s + 2) >> 2, d2 = (s + 2) & 3;
#pragma unroll
        for (int tn = 0; tn < 2; ++tn)
          Bb[(s + 2) % 3][tn] = *(const uint4*)&WhstF[bo[d2] + js2 * 512 + tn * 16384];
      }
      U af[4];
#pragma unroll
      for (int tm = 0; tm < 4; ++tm) {
        uint2 mb = Nn[cs][tm];
        u32 e0 = ((mb.x >> d) & 0x01010101u) * 0xFFu;
        u32 e1 = ((mb.y >> d) & 0x01010101u) * 0xFFu;
        af[tm].u.x = A[cs][tm].x & dup01(e0);
        af[tm].u.y = A[cs][tm].y & dup23(e0);
        af[tm].u.z = A[cs][tm].z & dup01(e1);
        af[tm].u.w = A[cs][tm].w & dup23(e1);
      }
#pragma unroll
      for (int tm = 0; tm < 4; ++tm)
#pragma unroll
        for (int tn = 0; tn < 2; ++tn) {
          U bb; bb.u = Bb[s % 3][tn];
          acc[tm][tn] = __builtin_amdgcn_mfma_f32_16x16x32_bf16(
              af[tm].h, bb.h, acc[tm][tn], 0, 0, 0);
        }
    }
  }
  u16* P = part + (size_t)ks * 2097152;
#pragma unroll
  for (int tm = 0; tm < 4; ++tm) {
#pragma unroll
    for (int tn = 0; tn < 2; ++tn) {
      int irow = (itb + tm) * 16 + quad * 4;
      int go = (otb + tn) * 16 + r16;
#pragma unroll
      for (int r = 0; r < 4; ++r)
        P[((size_t)b * 1024 + irow + r) * 256 + go] = f2bf(acc[tm][tn][r]);
    }
  }
}

// ---------------------------------------------------------------------------
// K7: out = 0.5 * sum_ks part[ks]  (bf16 -> fp32)
__global__ void k_reduce(const u16* __restrict__ part, float* __restrict__ out) {
  int idx = (blockIdx.x * 256 + threadIdx.x) * 8;
  float s[8];
#pragma unroll
  for (int k = 0; k < 8; ++k) s[k] = 0.f;
#pragma unroll
  for (int ks = 0; ks < 4; ++ks) {
    uint4 v = *(const uint4*)&part[(size_t)ks * 2097152 + idx];
    u32 ww[4] = {v.x, v.y, v.z, v.w};
#pragma unroll
    for (int k = 0; k < 4; ++k) {
      union { u32 i; float f; } lo, hi;
      lo.i = (ww[k] & 0xFFFFu) << 16;
      hi.i = ww[k] & 0xFFFF0000u;
      s[k * 2] += lo.f;
      s[k * 2 + 1] += hi.f;
    }
  }
  float4 o0 = {0.5f * s[0], 0.5f * s[1], 0.5f * s[2], 0.5f * s[3]};
  float4 o1 = {0.5f * s[4], 0.5f * s[5], 0.5f * s[6], 0.5f * s[7]};
  *(float4*)&out[idx] = o0;
  *(float4*)&out[idx + 4] = o1;
}

// ---------------------------------------------------------------------------
extern "C" void kernel_launch(void* const* d_in, const int* in_sizes, int n_in,
                              void* d_out, int out_size, void* d_ws, size_t ws_size,
                              hipStream_t stream) {
  const float* x = (const float*)d_in[0];
  const int* AU = (const int*)d_in[1];
  const int* AD = (const int*)d_in[2];
  const int* AR = (const int*)d_in[3];
  const int* AL = (const int*)d_in[4];
  const float* W = (const float*)d_in[5];
  const float* a = (const float*)d_in[6];
  float* out = (float*)d_out;

  char* ws = (char*)d_ws;
  u16* Wt = (u16*)(ws + 0);                      // 512 KB
  float* vsrc = (float*)(ws + 524288);           //   4 KB
  float* vdst = (float*)(ws + 528384);           //   4 KB
  float* es = (float*)(ws + 532480);             // 128 KB
  float* ed = (float*)(ws + 663552);             // 128 KB
  unsigned char* nibR = (unsigned char*)(ws + 794624);   // 1 MB
  unsigned char* nibF = (unsigned char*)(ws + 1843200);  // 1 MB
  u16* xb = (u16*)(ws + 2891776);                //   4 MB
  u16* WhstF = (u16*)(ws + 7086080);             //  16 MB
  u16* alphaF = (u16*)(ws + 23863296);           //  16 MB
  u16* part = (u16*)(ws + 40640512);             //  16 MB
  if (ws_size < 57417728) return;

  hipLaunchKernelGGL(k_prep, dim3(1600), dim3(256), 0, stream,
                     W, a, Wt, vsrc, vdst, AU, AD, AR, AL, nibR, nibF);
  hipLaunchKernelGGL(k_edots, dim3(512), dim3(256), 0, stream, x, vsrc, vdst, es, ed, xb);
  hipLaunchKernelGGL(k_mid, dim3(1024), dim3(256), 0, stream,
                     xb, Wt, WhstF, es, ed, nibR, alphaF);
  hipLaunchKernelGGL(k_agg, dim3(4, 32, 8), dim3(256), 0, stream, alphaF, nibF, WhstF, part);
  hipLaunchKernelGGL(k_reduce, dim3(1024), dim3(256), 0, stream, part, out);
}

// Round 11
// 156.978 us; speedup vs baseline: 1.0743x; 1.0743x over previous
//
#include <hip/hip_runtime.h>

// Problem constants
#define B_ 8
#define N_ 1024
#define F_ 256
#define O_ 256

typedef unsigned short u16;
typedef unsigned int u32;
typedef __attribute__((ext_vector_type(8))) short bf8;   // 8 bf16 (4 VGPRs) MFMA frag
typedef __attribute__((ext_vector_type(4))) float f4;    // 4 fp32 MFMA acc

__device__ __forceinline__ u16 f2bf(float f) {
  union { float f; u32 u; } c; c.f = f;
  u32 u = c.u;
  u32 r = u + 0x7FFFu + ((u >> 16) & 1u);  // RNE
  return (u16)(r >> 16);
}
__device__ __forceinline__ float bf2f(u16 u) {
  union { u32 i; float f; } c; c.i = ((u32)u) << 16; return c.f;
}

#if defined(__has_builtin)
#if __has_builtin(__builtin_amdgcn_perm)
#define HAVE_PERM 1
#endif
#endif
__device__ __forceinline__ u32 dup01(u32 e) {  // bytes (b0,b0,b1,b1)
#ifdef HAVE_PERM
  return __builtin_amdgcn_perm(e, e, 0x01010000u);
#else
  return (e & 0xFFu) * 0x0101u + (e & 0xFF00u) * 0x010100u;
#endif
}
__device__ __forceinline__ u32 dup23(u32 e) {  // bytes (b2,b2,b3,b3)
#ifdef HAVE_PERM
  return __builtin_amdgcn_perm(e, e, 0x03030202u);
#else
  return ((e >> 16) & 0xFFu) * 0x0101u + ((e >> 16) & 0xFF00u) * 0x010100u;
#endif
}

// ---------------------------------------------------------------------------
// K_prep: fused {W transpose+head-sum} | {vsrc/vdst dots} | {nibble masks}.
__global__ __launch_bounds__(256) void k_prep(const float* __restrict__ W,
                                              const float* __restrict__ a,
                                              u16* __restrict__ Wt,
                                              float* __restrict__ vsrc,
                                              float* __restrict__ vdst,
                                              const int* __restrict__ AU,
                                              const int* __restrict__ AD,
                                              const int* __restrict__ AR,
                                              const int* __restrict__ AL,
                                              unsigned char* __restrict__ nibR,
                                              unsigned char* __restrict__ nibF) {
  __shared__ u16 t[64][72];
  __shared__ float red[2][4];
  int bx = blockIdx.x;
  int tdx = threadIdx.x;
  if (bx < 64) {
    int d = bx >> 4, tile = bx & 15;
    int f0 = (tile >> 2) * 64, o0 = (tile & 3) * 64;
    const float* src0 = W + (d * 2 + 0) * 65536;
    const float* src1 = W + (d * 2 + 1) * 65536;
    u16* dst = Wt + d * 65536;
    for (int i = 0; i < 2; ++i) {
      int c = i * 256 + tdx;
      int row = c >> 3, cc = (c & 7) * 8;
      int base = (f0 + row) * 256 + o0 + cc;
      float4 a0 = *(const float4*)&src0[base];
      float4 a1 = *(const float4*)&src0[base + 4];
      float4 b0 = *(const float4*)&src1[base];
      float4 b1 = *(const float4*)&src1[base + 4];
      u16 tmp[8] __attribute__((aligned(16)));
      tmp[0] = f2bf(a0.x + b0.x); tmp[1] = f2bf(a0.y + b0.y);
      tmp[2] = f2bf(a0.z + b0.z); tmp[3] = f2bf(a0.w + b0.w);
      tmp[4] = f2bf(a1.x + b1.x); tmp[5] = f2bf(a1.y + b1.y);
      tmp[6] = f2bf(a1.z + b1.z); tmp[7] = f2bf(a1.w + b1.w);
      *(uint4*)&t[row][cc] = *(uint4*)tmp;
    }
    __syncthreads();
    for (int i = 0; i < 2; ++i) {
      int c = i * 256 + tdx;
      int orow = c >> 3, fc = (c & 7) * 8;
      u16 v[8] __attribute__((aligned(16)));
#pragma unroll
      for (int k = 0; k < 8; ++k) v[k] = t[fc + k][orow];
      *(uint4*)&dst[(o0 + orow) * 256 + f0 + fc] = *(uint4*)v;
    }
  } else if (bx < 1088) {
    int blk = bx - 64;
    int d = blk >> 8, f = blk & 255;
    int o = tdx;
    int dh = d * 2 + 1;
    float w = W[(dh * 256 + f) * 256 + o];
    float as = a[dh * 512 + o];
    float ad = a[dh * 512 + 256 + o];
    float ps = w * as, pd = w * ad;
    for (int off = 32; off; off >>= 1) {
      ps += __shfl_down(ps, off);
      pd += __shfl_down(pd, off);
    }
    int lane = o & 63, w4 = o >> 6;
    if (lane == 0) { red[0][w4] = ps; red[1][w4] = pd; }
    __syncthreads();
    if (o == 0) vsrc[d * 256 + f] = red[0][0] + red[0][1] + red[0][2] + red[0][3];
    if (o == 1) vdst[d * 256 + f] = red[1][0] + red[1][1] + red[1][2] + red[1][3];
  } else {
    int idx = (bx - 1088) * 256 + tdx;  // 131072: i*128 + j/8
    int i = idx >> 7;
    int jb = (idx & 127) * 8;
    int base = i * 1024 + jb;
    int4 au0 = *(const int4*)&AU[base], au1 = *(const int4*)&AU[base + 4];
    int4 ad0 = *(const int4*)&AD[base], ad1 = *(const int4*)&AD[base + 4];
    int4 ar0 = *(const int4*)&AR[base], ar1 = *(const int4*)&AR[base + 4];
    int4 al0 = *(const int4*)&AL[base], al1 = *(const int4*)&AL[base + 4];
    int u[8] = {au0.x, au0.y, au0.z, au0.w, au1.x, au1.y, au1.z, au1.w};
    int dn[8] = {ad0.x, ad0.y, ad0.z, ad0.w, ad1.x, ad1.y, ad1.z, ad1.w};
    int rr[8] = {ar0.x, ar0.y, ar0.z, ar0.w, ar1.x, ar1.y, ar1.z, ar1.w};
    int ll[8] = {al0.x, al0.y, al0.z, al0.w, al1.x, al1.y, al1.z, al1.w};
    unsigned char m[8] __attribute__((aligned(8)));
#pragma unroll
    for (int k = 0; k < 8; ++k)
      m[k] = (unsigned char)((u[k] ? 1u : 0u) | (dn[k] ? 2u : 0u) | (rr[k] ? 4u : 0u) | (ll[k] ? 8u : 0u));
    *(uint2*)&nibR[base] = *(uint2*)m;
    int it = i >> 4, jw = jb >> 5;
    int lane = ((jb >> 3) & 3) * 16 + (i & 15);
    *(uint2*)&nibF[((it * 32 + jw) * 64 + lane) * 8] = *(uint2*)m;
  }
}

// ---------------------------------------------------------------------------
// K2: wave-per-4-rows e-dots + xb emit.
__global__ __launch_bounds__(256) void k_edots(const float* __restrict__ x,
                                               const float* __restrict__ vsrc,
                                               const float* __restrict__ vdst,
                                               float* __restrict__ es,
                                               float* __restrict__ ed,
                                               u16* __restrict__ xb) {
  int t = threadIdx.x, lane = t & 63, w = t >> 6;
  int f4i = lane * 4;
  float4 vs[4], vd[4];
#pragma unroll
  for (int d = 0; d < 4; ++d) {
    vs[d] = *(const float4*)&vsrc[d * 256 + f4i];
    vd[d] = *(const float4*)&vdst[d * 256 + f4i];
  }
  int row0 = blockIdx.x * 16 + w * 4;  // 512 blocks x 16 rows
  for (int rr = 0; rr < 4; ++rr) {
    int row = row0 + rr;
    float4 xv = *(const float4*)&x[(size_t)row * 256 + f4i];
    u16 pk[4] __attribute__((aligned(8)));
    pk[0] = f2bf(xv.x); pk[1] = f2bf(xv.y); pk[2] = f2bf(xv.z); pk[3] = f2bf(xv.w);
    *(uint2*)&xb[(size_t)row * 256 + f4i] = *(uint2*)pk;
    float p[8];
#pragma unroll
    for (int d = 0; d < 4; ++d) {
      p[d] = xv.x * vs[d].x + xv.y * vs[d].y + xv.z * vs[d].z + xv.w * vs[d].w;
      p[4 + d] = xv.x * vd[d].x + xv.y * vd[d].y + xv.z * vd[d].z + xv.w * vd[d].w;
    }
#pragma unroll
    for (int v = 0; v < 8; ++v)
      for (int off = 32; off; off >>= 1) p[v] += __shfl_xor(p[v], off);
    if (lane == 0) {
      int b = row >> 10, n = row & 1023;
#pragma unroll
      for (int d = 0; d < 4; ++d) {
        es[(d * 8 + b) * 1024 + n] = p[d];
        ed[(d * 8 + b) * 1024 + n] = p[4 + d];
      }
    }
  }
}

// ---------------------------------------------------------------------------
// K_mid: fused {whsum MFMA GEMM (BK=64, 8 barriers)} | {softmax}.
__global__ __launch_bounds__(256, 2) void k_mid(const u16* __restrict__ X,
                                                const u16* __restrict__ Wt,
                                                u16* __restrict__ WhstF,
                                                const float* __restrict__ es,
                                                const float* __restrict__ ed,
                                                const unsigned char* __restrict__ nibR,
                                                u16* __restrict__ alphaF) {
  __shared__ char smem[51200];
  int bx = blockIdx.x;
  int t = threadIdx.x;
  int lane = t & 63, w = t >> 6;
  if (bx < 512) {
    // ---- whsum, BK=64 with 72-halfword padded stride (4-bank row rotation)
    u16* lA = (u16*)smem;                   // 128*72*2 = 18432 B
    u16* lB = (u16*)(smem + 18432);         // 18432 B
    u16* sC = (u16*)smem;                   // reused after K-loop (34816 B)
    int xo = bx & 1;
    int m0 = ((bx >> 1) & 63) * 128;
    int d = bx >> 7;
    int o0 = xo * 128;
    int wm = w >> 1, wn = w & 1;
    int r16 = lane & 15, quad = lane >> 4, q8 = quad * 8;
    f4 acc[4][4];
    const f4 fz = {0.f, 0.f, 0.f, 0.f};
#pragma unroll
    for (int i = 0; i < 4; ++i)
#pragma unroll
      for (int j = 0; j < 4; ++j) acc[i][j] = fz;

    const u16* Bp = Wt + d * 65536;
    for (int k0 = 0; k0 < 256; k0 += 64) {
      uint4 va[4], vb[4];
#pragma unroll
      for (int i = 0; i < 4; ++i) {
        int c = i * 256 + t;                 // 1024 chunks (16B) per tile
        int row = c >> 3, ko = (c & 7) * 8;  // 8 chunks per 64-wide row
        va[i] = *(const uint4*)&X[(size_t)(m0 + row) * 256 + k0 + ko];
        vb[i] = *(const uint4*)&Bp[(o0 + row) * 256 + k0 + ko];
      }
      __syncthreads();
#pragma unroll
      for (int i = 0; i < 4; ++i) {
        int c = i * 256 + t;
        int row = c >> 3, ko = (c & 7) * 8;
        *(uint4*)&lA[row * 72 + ko] = va[i];
        *(uint4*)&lB[row * 72 + ko] = vb[i];
      }
      __syncthreads();
#pragma unroll
      for (int sub = 0; sub < 2; ++sub) {
        bf8 af[4], bfr[4];
#pragma unroll
        for (int tm = 0; tm < 4; ++tm)
          af[tm] = *(const bf8*)&lA[(wm * 64 + tm * 16 + r16) * 72 + sub * 32 + q8];
#pragma unroll
        for (int tn = 0; tn < 4; ++tn)
          bfr[tn] = *(const bf8*)&lB[(wn * 64 + tn * 16 + r16) * 72 + sub * 32 + q8];
#pragma unroll
        for (int tm = 0; tm < 4; ++tm)
#pragma unroll
          for (int tn = 0; tn < 4; ++tn)
            acc[tm][tn] = __builtin_amdgcn_mfma_f32_16x16x32_bf16(
                af[tm], bfr[tn], acc[tm][tn], 0, 0, 0);
      }
    }
    __syncthreads();  // all waves done reading lA/lB; safe to overwrite with sC
#pragma unroll
    for (int tm = 0; tm < 4; ++tm) {
#pragma unroll
      for (int tn = 0; tn < 4; ++tn) {
        int o = wn * 64 + tn * 16 + r16;
        int n = wm * 64 + tm * 16 + quad * 4;
        u16 p[4] __attribute__((aligned(8)));
#pragma unroll
        for (int r = 0; r < 4; ++r) p[r] = f2bf(acc[tm][tn][r]);
        *(uint2*)&sC[o * 136 + n] = *(uint2*)p;
      }
    }
    __syncthreads();
    int b = m0 >> 10;
    int nlo = m0 & 1023;
    int dbbase = d * 8 + b;
    int otg0 = o0 >> 4, jwg0 = nlo >> 5;
#pragma unroll
    for (int cc = 0; cc < 8; ++cc) {
      int c = cc * 256 + t;
      int p = c >> 6, l = c & 63;
      int ot_l = p >> 2, jw_l = p & 3;
      int o_l = ot_l * 16 + (l & 15);
      int j_l = jw_l * 32 + (l >> 4) * 8;
      uint4 v = *(const uint4*)&sC[o_l * 136 + j_l];
      int off = (((dbbase * 16 + otg0 + ot_l) * 32 + jwg0 + jw_l) * 64 + l) * 8;
      *(uint4*)&WhstF[off] = v;
    }
  } else {
    // ---- softmax -> alphaF (frag-ordered). ed cached in LDS; single pass.
    float* sEd = (float*)smem;                       // 16384 B
    u16 (*sAl)[1032] = (u16(*)[1032])(smem + 16384); // 33024 B
    float* srs = (float*)(smem + 49408);             //    64 B
    int sx = bx - 512;
    int it = sx & 63, b = sx >> 6;
    const float NINF = -__builtin_inff();
#pragma unroll
    for (int c = 0; c < 4; ++c) {
      int q = c * 256 + t;
      int d = q >> 8, jc = (q & 255) * 4;
      *(float4*)&sEd[d * 1024 + jc] = *(const float4*)&ed[(size_t)(d * 8 + b) * 1024 + jc];
    }
    __syncthreads();
    for (int rr = 0; rr < 4; ++rr) {
      int r = w * 4 + rr;
      int i = it * 16 + r;
      float e0 = es[(0 * 8 + b) * 1024 + i];
      float e1 = es[(1 * 8 + b) * 1024 + i];
      float e2 = es[(2 * 8 + b) * 1024 + i];
      float e3 = es[(3 * 8 + b) * 1024 + i];
      unsigned mbv[16];
#pragma unroll
      for (int k = 0; k < 16; ++k) mbv[k] = nibR[i * 1024 + k * 64 + lane];
      float e[16];
      float mx = NINF;
#pragma unroll
      for (int k = 0; k < 16; ++k) {
        unsigned m = mbv[k];
        int d = m ? (31 - __clz((int)m)) : 0;
        float esd = d == 0 ? e0 : d == 1 ? e1 : d == 2 ? e2 : e3;
        float z = esd + sEd[d * 1024 + k * 64 + lane];
        float lz = z > 0.0f ? z : 0.01f * z;
        e[k] = m ? lz : NINF;
        mx = fmaxf(mx, e[k]);
      }
      for (int off = 32; off; off >>= 1) mx = fmaxf(mx, __shfl_xor(mx, off));
      float s = 0.f;
#pragma unroll
      for (int k = 0; k < 16; ++k) {
        float p = exp2f((e[k] - mx) * 1.4426950408889634f);
        s += p;
        sAl[r][k * 64 + lane] = f2bf(p);
      }
      for (int off = 32; off; off >>= 1) s += __shfl_xor(s, off);
      if (lane == 0) srs[r] = 1.0f / s;
    }
    __syncthreads();
#pragma unroll
    for (int cc = 0; cc < 8; ++cc) {
      int c = cc * 256 + t;
      int jw = c >> 6, l = c & 63;
      int i_l = l & 15;
      int j_l = jw * 32 + (l >> 4) * 8;
      uint4 v = *(const uint4*)&sAl[i_l][j_l];
      float rs = srs[i_l];
      u16 pk[8] __attribute__((aligned(16)));
      u32 wv[4] = {v.x, v.y, v.z, v.w};
#pragma unroll
      for (int k = 0; k < 4; ++k) {
        pk[k * 2] = f2bf(bf2f((u16)(wv[k] & 0xFFFFu)) * rs);
        pk[k * 2 + 1] = f2bf(bf2f((u16)(wv[k] >> 16)) * rs);
      }
      int off = (((b * 64 + it) * 32 + jw) * 64 + l) * 8;
      *(uint4*)&alphaF[off] = *(uint4*)pk;
    }
  }
}

// ---------------------------------------------------------------------------
// K6 (reverted to R9 config): 512 blocks, waves 64i x 64o (tn=4), B 4-slot
// rotation with 3-step lookahead (~230 cyc coverage), A/nib dbuf per js.
__global__ __launch_bounds__(256, 2) void k_agg(const u16* __restrict__ alphaF,
                                                const unsigned char* __restrict__ nibF,
                                                const u16* __restrict__ WhstF,
                                                u16* __restrict__ part) {
  int ob2 = blockIdx.x;        // 2: o-half (8 o-tiles each)
  int bz = blockIdx.y;         // 32: b*4 + ks
  int iz = blockIdx.z;         // 8: i-tile-128
  int b = bz >> 2, ks = bz & 3;
  int t = threadIdx.x, lane = t & 63, w = t >> 6;
  int wm = w >> 1, wn = w & 1;
  int r16 = lane & 15, quad = lane >> 4;
  int itb = iz * 8 + wm * 4;
  int otb = ob2 * 8 + wn * 4;
  int jw0 = ks * 8;

  int aoff[4], noff[4], bo[4];
#pragma unroll
  for (int tm = 0; tm < 4; ++tm) {
    aoff[tm] = (((b * 64 + itb + tm) * 32 + jw0) * 64 + lane) * 8;
    noff[tm] = (((itb + tm) * 32 + jw0) * 64 + lane) * 8;
  }
#pragma unroll
  for (int d = 0; d < 4; ++d)
    bo[d] = ((((d * 8 + b) * 16 + otb) * 32 + jw0) * 64 + lane) * 8;

  f4 acc[4][4];
  const f4 fz = {0.f, 0.f, 0.f, 0.f};
#pragma unroll
  for (int i = 0; i < 4; ++i)
#pragma unroll
    for (int j = 0; j < 4; ++j) acc[i][j] = fz;

  uint4 A[2][4];
  uint2 Nn[2][4];
  uint4 Bb[4][4];
  union U { uint4 u; bf8 h; };

#pragma unroll
  for (int tm = 0; tm < 4; ++tm) {
    A[0][tm] = *(const uint4*)&alphaF[aoff[tm]];
    Nn[0][tm] = *(const uint2*)&nibF[noff[tm]];
  }
#pragma unroll
  for (int s = 0; s < 3; ++s)
#pragma unroll
    for (int tn = 0; tn < 4; ++tn)
      Bb[s][tn] = *(const uint4*)&WhstF[bo[s & 3] + (s >> 2) * 512 + tn * 16384];

#pragma unroll
  for (int js = 0; js < 8; ++js) {
    int cs = js & 1;
    if (js < 7) {
#pragma unroll
      for (int tm = 0; tm < 4; ++tm) {
        A[cs ^ 1][tm] = *(const uint4*)&alphaF[aoff[tm] + (js + 1) * 512];
        Nn[cs ^ 1][tm] = *(const uint2*)&nibF[noff[tm] + (js + 1) * 512];
      }
    }
#pragma unroll
    for (int d = 0; d < 4; ++d) {
      int s = js * 4 + d;
      if (s + 3 < 32) {
        int js3 = (s + 3) >> 2, d3 = (s + 3) & 3;
#pragma unroll
        for (int tn = 0; tn < 4; ++tn)
          Bb[(s + 3) & 3][tn] = *(const uint4*)&WhstF[bo[d3] + js3 * 512 + tn * 16384];
      }
      U af[4];
#pragma unroll
      for (int tm = 0; tm < 4; ++tm) {
        uint2 mb = Nn[cs][tm];
        u32 e0 = ((mb.x >> d) & 0x01010101u) * 0xFFu;
        u32 e1 = ((mb.y >> d) & 0x01010101u) * 0xFFu;
        af[tm].u.x = A[cs][tm].x & dup01(e0);
        af[tm].u.y = A[cs][tm].y & dup23(e0);
        af[tm].u.z = A[cs][tm].z & dup01(e1);
        af[tm].u.w = A[cs][tm].w & dup23(e1);
      }
#pragma unroll
      for (int tm = 0; tm < 4; ++tm)
#pragma unroll
        for (int tn = 0; tn < 4; ++tn) {
          U bb; bb.u = Bb[s & 3][tn];
          acc[tm][tn] = __builtin_amdgcn_mfma_f32_16x16x32_bf16(
              af[tm].h, bb.h, acc[tm][tn], 0, 0, 0);
        }
    }
  }
  u16* P = part + (size_t)ks * 2097152;
#pragma unroll
  for (int tm = 0; tm < 4; ++tm) {
#pragma unroll
    for (int tn = 0; tn < 4; ++tn) {
      int irow = (itb + tm) * 16 + quad * 4;
      int go = (otb + tn) * 16 + r16;
#pragma unroll
      for (int r = 0; r < 4; ++r)
        P[((size_t)b * 1024 + irow + r) * 256 + go] = f2bf(acc[tm][tn][r]);
    }
  }
}

// ---------------------------------------------------------------------------
// K7: out = 0.5 * sum_ks part[ks]  (bf16 -> fp32)
__global__ void k_reduce(const u16* __restrict__ part, float* __restrict__ out) {
  int idx = (blockIdx.x * 256 + threadIdx.x) * 8;
  float s[8];
#pragma unroll
  for (int k = 0; k < 8; ++k) s[k] = 0.f;
#pragma unroll
  for (int ks = 0; ks < 4; ++ks) {
    uint4 v = *(const uint4*)&part[(size_t)ks * 2097152 + idx];
    u32 ww[4] = {v.x, v.y, v.z, v.w};
#pragma unroll
    for (int k = 0; k < 4; ++k) {
      union { u32 i; float f; } lo, hi;
      lo.i = (ww[k] & 0xFFFFu) << 16;
      hi.i = ww[k] & 0xFFFF0000u;
      s[k * 2] += lo.f;
      s[k * 2 + 1] += hi.f;
    }
  }
  float4 o0 = {0.5f * s[0], 0.5f * s[1], 0.5f * s[2], 0.5f * s[3]};
  float4 o1 = {0.5f * s[4], 0.5f * s[5], 0.5f * s[6], 0.5f * s[7]};
  *(float4*)&out[idx] = o0;
  *(float4*)&out[idx + 4] = o1;
}

// ---------------------------------------------------------------------------
extern "C" void kernel_launch(void* const* d_in, const int* in_sizes, int n_in,
                              void* d_out, int out_size, void* d_ws, size_t ws_size,
                              hipStream_t stream) {
  const float* x = (const float*)d_in[0];
  const int* AU = (const int*)d_in[1];
  const int* AD = (const int*)d_in[2];
  const int* AR = (const int*)d_in[3];
  const int* AL = (const int*)d_in[4];
  const float* W = (const float*)d_in[5];
  const float* a = (const float*)d_in[6];
  float* out = (float*)d_out;

  char* ws = (char*)d_ws;
  u16* Wt = (u16*)(ws + 0);                      // 512 KB
  float* vsrc = (float*)(ws + 524288);           //   4 KB
  float* vdst = (float*)(ws + 528384);           //   4 KB
  float* es = (float*)(ws + 532480);             // 128 KB
  float* ed = (float*)(ws + 663552);             // 128 KB
  unsigned char* nibR = (unsigned char*)(ws + 794624);   // 1 MB
  unsigned char* nibF = (unsigned char*)(ws + 1843200);  // 1 MB
  u16* xb = (u16*)(ws + 2891776);                //   4 MB
  u16* WhstF = (u16*)(ws + 7086080);             //  16 MB
  u16* alphaF = (u16*)(ws + 23863296);           //  16 MB
  u16* part = (u16*)(ws + 40640512);             //  16 MB
  if (ws_size < 57417728) return;

  hipLaunchKernelGGL(k_prep, dim3(1600), dim3(256), 0, stream,
                     W, a, Wt, vsrc, vdst, AU, AD, AR, AL, nibR, nibF);
  hipLaunchKernelGGL(k_edots, dim3(512), dim3(256), 0, stream, x, vsrc, vdst, es, ed, xb);
  hipLaunchKernelGGL(k_mid, dim3(1024), dim3(256), 0, stream,
                     xb, Wt, WhstF, es, ed, nibR, alphaF);
  hipLaunchKernelGGL(k_agg, dim3(2, 32, 8), dim3(256), 0, stream, alphaF, nibF, WhstF, part);
  hipLaunchKernelGGL(k_reduce, dim3(1024), dim3(256), 0, stream, part, out);
}